// Round 10
// baseline (144.149 us; speedup 1.0000x reference)
//
#include <hip/hip_runtime.h>
#include <math.h>

#define NHF 128
#define NRBF 50
#define LAYERS 3
#define CUTOFF_F 5.0f
#define STEP_F (CUTOFF_F/49.0f)
#define LOG2_F 0.6931471805599453f
#define PI_F 3.14159265358979323846f
#define TBL 4096
#define TROWS (TBL+1)
#define TINV ((float)TBL / CUTOFF_F)

typedef __attribute__((ext_vector_type(8))) _Float16 fp16x8;
typedef __attribute__((ext_vector_type(4))) float f32x4;
typedef _Float16 f16x2 __attribute__((ext_vector_type(2)));

static __device__ __forceinline__ unsigned short f2h(float f){
    return __builtin_bit_cast(unsigned short, (_Float16)f);   // RNE
}
// RNE pack (NOT cvt_pkrtz, which is round-toward-zero)
static __device__ __forceinline__ unsigned packh(float lo, float hi){
    return (unsigned)f2h(lo) | ((unsigned)f2h(hi) << 16);
}
// fast shifted-softplus: max(x,0) + ln2*(log2(1+2^(-|x|*log2e)) - 1); |err| ~1e-6
static __device__ __forceinline__ float sspf(float x){
    float t = exp2f(-fabsf(x) * 1.44269504f);
    return fmaxf(x, 0.0f) + 0.69314718f * (log2f(1.0f + t) - 1.0f);
}
static __device__ __forceinline__ float4 ld4(const float* p){ return *reinterpret_cast<const float4*>(p); }

// ---- pack 9 weight matrices [128][128] f32 -> f16 MFMA fragment order ----
// frag (g, ks, cf): lane l, elem j = W[ks*32 + (l>>4)*8 + j][cf*16 + (l&15)]
__global__ __launch_bounds__(256) void k_pack(const float* __restrict__ in2f_W, const float* __restrict__ o_W1,
                                              const float* __restrict__ o_W2, uint4* __restrict__ Wp){
    int tid = blockIdx.x * 256 + threadIdx.x;      // 9*2048 total
    if (tid >= 9 * 2048) return;
    int g = tid >> 11;
    int rem = tid & 2047;
    int s = rem >> 9;
    int f = (rem >> 6) & 7;
    int l = rem & 63;
    int layer = g / 3, type = g % 3;
    const float* src = (type == 0 ? in2f_W : (type == 1 ? o_W1 : o_W2)) + (size_t)layer * NHF * NHF;
    int row0 = s * 32 + ((l >> 4) << 3);
    int col  = (f << 4) + (l & 15);
    unsigned p0, p1, p2, p3;
    p0 = (unsigned)f2h(src[(row0+0)*NHF + col]) | ((unsigned)f2h(src[(row0+1)*NHF + col]) << 16);
    p1 = (unsigned)f2h(src[(row0+2)*NHF + col]) | ((unsigned)f2h(src[(row0+3)*NHF + col]) << 16);
    p2 = (unsigned)f2h(src[(row0+4)*NHF + col]) | ((unsigned)f2h(src[(row0+5)*NHF + col]) << 16);
    p3 = (unsigned)f2h(src[(row0+6)*NHF + col]) | ((unsigned)f2h(src[(row0+7)*NHF + col]) << 16);
    Wp[tid] = make_uint4(p0, p1, p2, p3);
}

// ---- fused filter table (f16): T[l][t][c] = f16( (ssp(rbf(r_t)@W1+b1)@W2+b2) * dc(r_t) ) ----
__global__ __launch_bounds__(256) void k_table(const float* __restrict__ W1, const float* __restrict__ b1,
                                               const float* __restrict__ W2, const float* __restrict__ b2,
                                               unsigned short* __restrict__ Th){
    __shared__ float rbfL[2][4][52];
    __shared__ float hidL[2][4][128];
    int l = blockIdx.y;
    int tid = threadIdx.x;
    int g = tid >> 7, c = tid & 127;
    const float* W1l = W1 + (size_t)l * NRBF * NHF;
    const float* W2l = W2 + (size_t)l * NHF * NHF;
    int t0 = blockIdx.x * 8 + g * 4;
    const float coeff = -0.5f / (STEP_F * STEP_F) * 1.44269504f;   // fold log2e into exp2
    const float dr = CUTOFF_F / (float)TBL;
    if (c < NRBF){
        float off = c * STEP_F;
        #pragma unroll
        for (int i = 0; i < 4; i++){
            int t = t0 + i; if (t > TBL) t = TBL;
            float d = t * dr - off;
            rbfL[g][i][c] = exp2f(coeff * d * d);
        }
    }
    __syncthreads();
    float acc[4];
    float bc = b1[l * NHF + c];
    #pragma unroll
    for (int i = 0; i < 4; i++) acc[i] = bc;
    for (int j = 0; j < NRBF; j++){
        float wv = W1l[j * NHF + c];
        #pragma unroll
        for (int i = 0; i < 4; i++) acc[i] = fmaf(rbfL[g][i][j], wv, acc[i]);
    }
    #pragma unroll
    for (int i = 0; i < 4; i++) hidL[g][i][c] = sspf(acc[i]);
    __syncthreads();
    float b2c = b2[l * NHF + c];
    #pragma unroll
    for (int i = 0; i < 4; i++) acc[i] = b2c;
    for (int j = 0; j < NHF; j++){
        float wv = W2l[j * NHF + c];
        #pragma unroll
        for (int i = 0; i < 4; i++) acc[i] = fmaf(hidL[g][i][j], wv, acc[i]);
    }
    #pragma unroll
    for (int i = 0; i < 4; i++){
        int t = t0 + i; if (t > TBL) t = TBL;
        float r = t * dr;
        float dc = (t >= TBL) ? 0.0f : 0.5f * (cosf(r * (PI_F / CUTOFF_F)) + 1.0f);
        float v = acc[i] * dc;
        Th[((size_t)l * TROWS + t) * NHF + c] = f2h(v);
    }
}

// ---- MFMA fragment loads ----
// activations (B-operand): lane l -> atom row rfbase+(l&15), k-pairs ks*16+(l>>4)*4+{0..3}
static __device__ __forceinline__ fp16x8 ldX(const unsigned* A_u, int rfbase, int ks, int l){
    int row = rfbase + (l & 15);
    int wc = ks * 16 + ((l >> 4) << 2);
    uint4 v = *reinterpret_cast<const uint4*>(&A_u[row * 64 + (wc ^ ((row & 7) << 2))]);
    return __builtin_bit_cast(fp16x8, v);
}
// weights (A-operand): pre-packed fragment order
static __device__ __forceinline__ fp16x8 ldW(const uint4* __restrict__ Wp, int g, int ks, int cfg, int l){
    uint4 v = Wp[(((g << 2) + ks) * 8 + cfg) * 64 + l];
    return __builtin_bit_cast(fp16x8, v);
}

// D^T = W^T @ X^T: lane owns 4 consecutive channels of one atom -> no cross-lane epilogue.
// EPI 0: D -> dst.  EPI 1: ssp(D + bias) -> dst.  EPI 2: hreg += D + bias; -> dst
template<int EPI>
static __device__ __forceinline__ void gemm_phase(const uint4* __restrict__ Wp, int g,
                                                  const unsigned* A_u, uint2* D2,
                                                  float hreg[2][2][4], const float* __restrict__ bias,
                                                  int w, int l){
    f32x4 acc00 = {0,0,0,0}, acc01 = {0,0,0,0}, acc10 = {0,0,0,0}, acc11 = {0,0,0,0};
    #pragma unroll
    for (int ks = 0; ks < 4; ks++){
        fp16x8 wa0 = ldW(Wp, g, ks, w * 2 + 0, l);
        fp16x8 wa1 = ldW(Wp, g, ks, w * 2 + 1, l);
        fp16x8 xb0 = ldX(A_u, 0, ks, l);
        fp16x8 xb1 = ldX(A_u, 16, ks, l);
        acc00 = __builtin_amdgcn_mfma_f32_16x16x32_f16(wa0, xb0, acc00, 0, 0, 0);
        acc01 = __builtin_amdgcn_mfma_f32_16x16x32_f16(wa0, xb1, acc01, 0, 0, 0);
        acc10 = __builtin_amdgcn_mfma_f32_16x16x32_f16(wa1, xb0, acc10, 0, 0, 0);
        acc11 = __builtin_amdgcn_mfma_f32_16x16x32_f16(wa1, xb1, acc11, 0, 0, 0);
    }
    #pragma unroll
    for (int chf = 0; chf < 2; chf++){
        int ch0 = (w * 2 + chf) * 16 + ((l >> 4) << 2);
        float4 bv = {0,0,0,0};
        if (EPI >= 1) bv = ld4(bias + ch0);
        #pragma unroll
        for (int af = 0; af < 2; af++){
            f32x4 a = (chf == 0) ? (af == 0 ? acc00 : acc01) : (af == 0 ? acc10 : acc11);
            int atom = af * 16 + (l & 15);
            float v0 = a[0] + bv.x, v1 = a[1] + bv.y, v2 = a[2] + bv.z, v3 = a[3] + bv.w;
            if (EPI == 1){ v0 = sspf(v0); v1 = sspf(v1); v2 = sspf(v2); v3 = sspf(v3); }
            if (EPI == 2){
                v0 += hreg[chf][af][0]; hreg[chf][af][0] = v0;
                v1 += hreg[chf][af][1]; hreg[chf][af][1] = v1;
                v2 += hreg[chf][af][2]; hreg[chf][af][2] = v2;
                v3 += hreg[chf][af][3]; hreg[chf][af][3] = v3;
            }
            D2[(atom << 5) + (((ch0 >> 2) ^ ((atom & 7) << 1)))] = make_uint2(packh(v0, v1), packh(v2, v3));
        }
    }
}

// ---- mega kernel: one block = one molecule, all 3 layers + per-molecule decoder ----
__global__ __launch_bounds__(256, 4) void k_mega(const int* __restrict__ z, const float* __restrict__ coord,
                                                 const float* __restrict__ emask, const float* __restrict__ amask,
                                                 const float* __restrict__ emb,
                                                 const uint4* __restrict__ Wp,
                                                 const float* __restrict__ o_b1, const float* __restrict__ o_b2,
                                                 const unsigned* __restrict__ Tb,
                                                 const float* __restrict__ dW1, const float* __restrict__ db1,
                                                 const float* __restrict__ dW2, const float* __restrict__ db2,
                                                 float* __restrict__ tempv, int nn){
    __shared__ __align__(16) unsigned hbf[32 * 64];     // f16 h (X input)
    __shared__ __align__(16) unsigned xfb[32 * 64];     // xf / t (f16)
    __shared__ __align__(16) unsigned mbu[32 * 64];     // edge messages m (f16)
    __shared__ int      pkE[32 * 32];                   // col | (t<<8)
    __shared__ int      cntL[32];
    __shared__ int      cntQ[8];
    __shared__ int      zL[32];
    __shared__ unsigned maskL[32];
    __shared__ float    cxyz[96];
    __shared__ float    amL[32];
    __shared__ float    hsb[NHF];

    int mol = blockIdx.x;
    int tid = threadIdx.x;
    int w = tid >> 6, l = tid & 63;
    int molA = mol * nn;
    int km = nn - 1;
    int ne = nn * km;

    uint2* hbf2 = reinterpret_cast<uint2*>(hbf);
    uint2* xfb2 = reinterpret_cast<uint2*>(xfb);

    // ---- cooperative staging ----
    if (tid < 32){ maskL[tid] = 0u; cntL[tid] = 0; }
    if (tid < 3 * nn) cxyz[tid] = coord[(size_t)molA * 3 + tid];
    if (tid < 32)     amL[tid] = (tid < nn) ? amask[molA + tid] : 0.0f;
    if (tid < 32)     zL[tid]  = (tid < nn) ? z[molA + tid] : 0;
    __syncthreads();
    for (int e = tid; e < ne; e += 256){
        if (emask[(size_t)molA * km + e] != 0.0f){
            int a = e / km, k = e - a * km;
            atomicOr(&maskL[a], 1u << k);
        }
    }

    // ---- h init: registers [chf][af][r] (ch-major C-layout) + f16 LDS copy ----
    float hreg[2][2][4];
    #pragma unroll
    for (int chf = 0; chf < 2; chf++){
        int ch0 = (w * 2 + chf) * 16 + ((l >> 4) << 2);
        #pragma unroll
        for (int af = 0; af < 2; af++){
            int atom = af * 16 + (l & 15);
            float4 v = {0,0,0,0};
            if (atom < nn) v = ld4(emb + (size_t)zL[atom] * NHF + ch0);
            hreg[chf][af][0] = v.x; hreg[chf][af][1] = v.y;
            hreg[chf][af][2] = v.z; hreg[chf][af][3] = v.w;
            hbf2[(atom << 5) + (((ch0 >> 2) ^ ((atom & 7) << 1)))] = make_uint2(packh(v.x, v.y), packh(v.z, v.w));
        }
    }
    __syncthreads();

    // ---- per-atom active-edge lists ----
    if (tid < nn){
        int ai = tid;
        unsigned msk = maskL[ai];
        float ax = cxyz[ai*3], ay = cxyz[ai*3+1], az = cxyz[ai*3+2];
        int cnt = 0;
        for (int k = 0; k < km; k++){
            int nb = k + (k >= ai ? 1 : 0);
            float dx = ax - cxyz[nb*3], dy = ay - cxyz[nb*3+1], dz = az - cxyz[nb*3+2];
            float r = sqrtf(dx*dx + dy*dy + dz*dz);
            int t = (int)(r * TINV + 0.5f);
            if (((msk >> k) & 1u) && t < TBL){
                pkE[ai * 32 + cnt] = nb | (t << 8);
                cnt++;
            }
        }
        cntL[ai] = cnt;
    }
    __syncthreads();
    // pad each atom's list to quad-max (multiple of 2); dummy -> T row TBL (zeros)
    if (tid < 32){
        int b4 = tid & ~3;
        int m0 = cntL[b4], m1 = cntL[b4+1], m2 = cntL[b4+2], m3 = cntL[b4+3];
        int mx = max(max(m0, m1), max(m2, m3));
        mx = (mx + 1) & ~1;
        for (int k = cntL[tid]; k < mx; k++) pkE[tid * 32 + k] = (TBL << 8);
        if (!(tid & 3)) cntQ[tid >> 2] = mx;
    }
    __syncthreads();

    int j16 = l & 15, g16 = l >> 4;
    for (int L = 0; L < LAYERS; L++){
        // in2f: xf = h @ W (no bias)
        gemm_phase<0>(Wp, L * 3 + 0, hbf, xfb2, hreg, o_b1, w, l);
        __syncthreads();
        // edge messages: 4 atoms/wave, 8 ch/lane, uint4 loads, f32 accumulation (v_fma_mix)
        const char* Tlj = (const char*)(Tb + (size_t)L * TROWS * 64) + (j16 << 4);
        for (int q = w; q < 8; q += 4){
            int a = (q << 2) + g16;
            int cnt = cntQ[q];
            const int* pe = &pkE[a * 32];
            float accf[8] = {0,0,0,0,0,0,0,0};
            for (int k = 0; k < cnt; k += 2){
                #pragma unroll
                for (int jj = 0; jj < 2; jj++){
                    int p = pe[k + jj];
                    uint4 tw = *reinterpret_cast<const uint4*>(Tlj + (p & ~0xFF));
                    int ca = p & 31;
                    uint4 xw = *reinterpret_cast<const uint4*>(&xfb[(ca << 6) + ((j16 ^ (ca & 7)) << 2)]);
                    f16x2 t0 = __builtin_bit_cast(f16x2, tw.x), t1 = __builtin_bit_cast(f16x2, tw.y);
                    f16x2 t2 = __builtin_bit_cast(f16x2, tw.z), t3 = __builtin_bit_cast(f16x2, tw.w);
                    f16x2 x0 = __builtin_bit_cast(f16x2, xw.x), x1 = __builtin_bit_cast(f16x2, xw.y);
                    f16x2 x2 = __builtin_bit_cast(f16x2, xw.z), x3 = __builtin_bit_cast(f16x2, xw.w);
                    accf[0] += (float)t0[0] * (float)x0[0];
                    accf[1] += (float)t0[1] * (float)x0[1];
                    accf[2] += (float)t1[0] * (float)x1[0];
                    accf[3] += (float)t1[1] * (float)x1[1];
                    accf[4] += (float)t2[0] * (float)x2[0];
                    accf[5] += (float)t2[1] * (float)x2[1];
                    accf[6] += (float)t3[0] * (float)x3[0];
                    accf[7] += (float)t3[1] * (float)x3[1];
                }
            }
            *reinterpret_cast<uint4*>(&mbu[(a << 6) + ((j16 ^ (a & 7)) << 2)]) =
                make_uint4(packh(accf[0], accf[1]), packh(accf[2], accf[3]),
                           packh(accf[4], accf[5]), packh(accf[6], accf[7]));
        }
        __syncthreads();
        // o1: t = ssp(m @ W + b1)
        gemm_phase<1>(Wp, L * 3 + 1, mbu, xfb2, hreg, o_b1 + L * NHF, w, l);
        __syncthreads();
        // o2: h(reg) += t @ W + b2 ; refresh h f16 copy
        gemm_phase<2>(Wp, L * 3 + 2, xfb, hbf2, hreg, o_b2 + L * NHF, w, l);
        __syncthreads();
    }

    // ---- readout: sum over atoms (cross-lane over l&15) + decoder -> tempv[mol] ----
    {
        float s[2][4];
        #pragma unroll
        for (int chf = 0; chf < 2; chf++)
            #pragma unroll
            for (int r = 0; r < 4; r++)
                s[chf][r] = hreg[chf][0][r] * amL[l & 15] + hreg[chf][1][r] * amL[16 + (l & 15)];
        #pragma unroll
        for (int o = 1; o < 16; o <<= 1){
            #pragma unroll
            for (int chf = 0; chf < 2; chf++)
                #pragma unroll
                for (int r = 0; r < 4; r++)
                    s[chf][r] += __shfl_xor(s[chf][r], o);
        }
        if (!(l & 15)){
            #pragma unroll
            for (int chf = 0; chf < 2; chf++)
                #pragma unroll
                for (int r = 0; r < 4; r++)
                    hsb[(w * 2 + chf) * 16 + ((l >> 4) << 2) + r] = s[chf][r];
        }
    }
    __syncthreads();
    // decoder: 256 threads = 64 outputs x 4 c-partitions, reduce in LDS (reuse pkE)
    {
        float* red = (float*)pkE;
        int o = tid & 63, part = tid >> 6;
        float u = 0.0f;
        #pragma unroll 8
        for (int c = part * 32; c < part * 32 + 32; c++)
            u = fmaf(hsb[c], dW1[c * 64 + o], u);
        red[part * 64 + o] = u;
    }
    __syncthreads();
    if (tid < 64){
        float u = ((float*)pkE)[tid] + ((float*)pkE)[64 + tid] + ((float*)pkE)[128 + tid]
                + ((float*)pkE)[192 + tid] + db1[tid];
        float p = sspf(u) * dW2[tid];
        #pragma unroll
        for (int o = 32; o > 0; o >>= 1) p += __shfl_down(p, o);
        if (tid == 0) tempv[mol] = p + db2[0];
    }
}

// ---- deterministic reaction scatter: pred[r] = sum_mol [ridx==r] temp*rsign (fixed order) ----
__global__ __launch_bounds__(256) void k_pred(const float* __restrict__ tempv, const int* __restrict__ ridx,
                                              const float* __restrict__ rsign, float* __restrict__ pred,
                                              int nmol, int nreact){
    extern __shared__ float sh[];                 // [nmol] temp*rsign, then [nmol] ridx
    float* tv = sh;
    int*   ri = (int*)(sh + nmol);
    int tid = threadIdx.x;
    for (int i = tid; i < nmol; i += 256){
        tv[i] = tempv[i] * rsign[i];
        ri[i] = ridx[i];
    }
    __syncthreads();
    int r = blockIdx.x * 256 + tid;
    if (r >= nreact) return;
    float s = 0.0f;
    for (int i = 0; i < nmol; i++)
        if (ri[i] == r) s += tv[i];
    pred[r] = s;
}

extern "C" void kernel_launch(void* const* d_in, const int* in_sizes, int n_in,
                              void* d_out, int out_size, void* d_ws, size_t ws_size,
                              hipStream_t stream){
    const int*   z      = (const int*)  d_in[0];
    const float* coord  = (const float*)d_in[1];
    const float* amask  = (const float*)d_in[3];
    const float* emask  = (const float*)d_in[4];
    const int*   ridx   = (const int*)  d_in[5];
    const float* rsign  = (const float*)d_in[6];
    const float* emb    = (const float*)d_in[7];
    const float* in2f_W = (const float*)d_in[10];
    const float* f_W1   = (const float*)d_in[11];
    const float* f_b1   = (const float*)d_in[12];
    const float* f_W2   = (const float*)d_in[13];
    const float* f_b2   = (const float*)d_in[14];
    const float* o_W1   = (const float*)d_in[15];
    const float* o_b1   = (const float*)d_in[16];
    const float* o_W2   = (const float*)d_in[17];
    const float* o_b2   = (const float*)d_in[18];
    const float* dW1    = (const float*)d_in[19];
    const float* db1    = (const float*)d_in[20];
    const float* dW2    = (const float*)d_in[21];
    const float* db2    = (const float*)d_in[22];

    const int N  = in_sizes[0];
    const int B  = in_sizes[5];
    const int nn = N / B;
    (void)n_in; (void)ws_size;

    // workspace carve
    uint4*    Wp    = (uint4*)d_ws;                                      // 294912 B
    unsigned* Tb    = (unsigned*)((char*)d_ws + 9 * 2048 * 16);          // LAYERS*TROWS*256 B
    float*    tempv = (float*)((char*)Tb + (size_t)LAYERS * TROWS * 256);// B floats

    k_pack <<<72, 256, 0, stream>>>(in2f_W, o_W1, o_W2, Wp);
    k_table<<<dim3((TROWS + 7) / 8, LAYERS), 256, 0, stream>>>(f_W1, f_b1, f_W2, f_b2,
                                                               (unsigned short*)Tb);
    k_mega <<<B, 256, 0, stream>>>(z, coord, emask, amask, emb, Wp, o_b1, o_b2, Tb,
                                   dW1, db1, dW2, db2, tempv, nn);
    k_pred <<<(out_size + 255) / 256, 256, B * 8, stream>>>(tempv, ridx, rsign,
                                                            (float*)d_out, B, out_size);
}

// Round 11
// 101.316 us; speedup vs baseline: 1.4228x; 1.4228x over previous
//
#include <hip/hip_runtime.h>
#include <math.h>

#define NHF 128
#define NRBF 50
#define LAYERS 3
#define CUTOFF_F 5.0f
#define STEP_F (CUTOFF_F/49.0f)
#define LOG2_F 0.6931471805599453f
#define PI_F 3.14159265358979323846f
#define TBL 4096
#define TROWS (TBL+1)
#define TINV ((float)TBL / CUTOFF_F)

typedef __attribute__((ext_vector_type(8))) _Float16 fp16x8;
typedef __attribute__((ext_vector_type(4))) float f32x4;
typedef _Float16 f16x2 __attribute__((ext_vector_type(2)));

static __device__ __forceinline__ unsigned short f2h(float f){
    return __builtin_bit_cast(unsigned short, (_Float16)f);   // RNE
}
// RNE pack (NOT cvt_pkrtz, which is round-toward-zero)
static __device__ __forceinline__ unsigned packh(float lo, float hi){
    return (unsigned)f2h(lo) | ((unsigned)f2h(hi) << 16);
}
// fast shifted-softplus: max(x,0) + ln2*(log2(1+2^(-|x|*log2e)) - 1); |err| ~1e-6
static __device__ __forceinline__ float sspf(float x){
    float t = exp2f(-fabsf(x) * 1.44269504f);
    return fmaxf(x, 0.0f) + 0.69314718f * (log2f(1.0f + t) - 1.0f);
}
static __device__ __forceinline__ float4 ld4(const float* p){ return *reinterpret_cast<const float4*>(p); }

// ---- pack 9 weight matrices [128][128] f32 -> f16 MFMA fragment order ----
// frag (g, ks, cf): lane l, elem j = W[ks*32 + (l>>4)*8 + j][cf*16 + (l&15)]
__global__ __launch_bounds__(256) void k_pack(const float* __restrict__ in2f_W, const float* __restrict__ o_W1,
                                              const float* __restrict__ o_W2, uint4* __restrict__ Wp){
    int tid = blockIdx.x * 256 + threadIdx.x;      // 9*2048 total
    if (tid >= 9 * 2048) return;
    int g = tid >> 11;
    int rem = tid & 2047;
    int s = rem >> 9;
    int f = (rem >> 6) & 7;
    int l = rem & 63;
    int layer = g / 3, type = g % 3;
    const float* src = (type == 0 ? in2f_W : (type == 1 ? o_W1 : o_W2)) + (size_t)layer * NHF * NHF;
    int row0 = s * 32 + ((l >> 4) << 3);
    int col  = (f << 4) + (l & 15);
    unsigned p0, p1, p2, p3;
    p0 = (unsigned)f2h(src[(row0+0)*NHF + col]) | ((unsigned)f2h(src[(row0+1)*NHF + col]) << 16);
    p1 = (unsigned)f2h(src[(row0+2)*NHF + col]) | ((unsigned)f2h(src[(row0+3)*NHF + col]) << 16);
    p2 = (unsigned)f2h(src[(row0+4)*NHF + col]) | ((unsigned)f2h(src[(row0+5)*NHF + col]) << 16);
    p3 = (unsigned)f2h(src[(row0+6)*NHF + col]) | ((unsigned)f2h(src[(row0+7)*NHF + col]) << 16);
    Wp[tid] = make_uint4(p0, p1, p2, p3);
}

// ---- fused filter table (f16): T[l][t][c] = f16( (ssp(rbf(r_t)@W1+b1)@W2+b2) * dc(r_t) ) ----
__global__ __launch_bounds__(256) void k_table(const float* __restrict__ W1, const float* __restrict__ b1,
                                               const float* __restrict__ W2, const float* __restrict__ b2,
                                               unsigned short* __restrict__ Th){
    __shared__ float rbfL[2][4][52];
    __shared__ float hidL[2][4][128];
    int l = blockIdx.y;
    int tid = threadIdx.x;
    int g = tid >> 7, c = tid & 127;
    const float* W1l = W1 + (size_t)l * NRBF * NHF;
    const float* W2l = W2 + (size_t)l * NHF * NHF;
    int t0 = blockIdx.x * 8 + g * 4;
    const float coeff = -0.5f / (STEP_F * STEP_F) * 1.44269504f;   // fold log2e into exp2
    const float dr = CUTOFF_F / (float)TBL;
    if (c < NRBF){
        float off = c * STEP_F;
        #pragma unroll
        for (int i = 0; i < 4; i++){
            int t = t0 + i; if (t > TBL) t = TBL;
            float d = t * dr - off;
            rbfL[g][i][c] = exp2f(coeff * d * d);
        }
    }
    __syncthreads();
    float acc[4];
    float bc = b1[l * NHF + c];
    #pragma unroll
    for (int i = 0; i < 4; i++) acc[i] = bc;
    for (int j = 0; j < NRBF; j++){
        float wv = W1l[j * NHF + c];
        #pragma unroll
        for (int i = 0; i < 4; i++) acc[i] = fmaf(rbfL[g][i][j], wv, acc[i]);
    }
    #pragma unroll
    for (int i = 0; i < 4; i++) hidL[g][i][c] = sspf(acc[i]);
    __syncthreads();
    float b2c = b2[l * NHF + c];
    #pragma unroll
    for (int i = 0; i < 4; i++) acc[i] = b2c;
    for (int j = 0; j < NHF; j++){
        float wv = W2l[j * NHF + c];
        #pragma unroll
        for (int i = 0; i < 4; i++) acc[i] = fmaf(hidL[g][i][j], wv, acc[i]);
    }
    #pragma unroll
    for (int i = 0; i < 4; i++){
        int t = t0 + i; if (t > TBL) t = TBL;
        float r = t * dr;
        float dc = (t >= TBL) ? 0.0f : 0.5f * (cosf(r * (PI_F / CUTOFF_F)) + 1.0f);
        float v = acc[i] * dc;
        Th[((size_t)l * TROWS + t) * NHF + c] = f2h(v);
    }
}

// ---- MFMA fragment loads ----
// activations (B-operand): lane l -> atom row rfbase+(l&15), k-pairs ks*16+(l>>4)*4+{0..3}
static __device__ __forceinline__ fp16x8 ldX(const unsigned* A_u, int rfbase, int ks, int l){
    int row = rfbase + (l & 15);
    int wc = ks * 16 + ((l >> 4) << 2);
    uint4 v = *reinterpret_cast<const uint4*>(&A_u[row * 64 + (wc ^ ((row & 7) << 2))]);
    return __builtin_bit_cast(fp16x8, v);
}
// weights (A-operand): pre-packed fragment order
static __device__ __forceinline__ fp16x8 ldW(const uint4* __restrict__ Wp, int g, int ks, int cfg, int l){
    uint4 v = Wp[(((g << 2) + ks) * 8 + cfg) * 64 + l];
    return __builtin_bit_cast(fp16x8, v);
}

// D^T = W^T @ X^T: lane owns 4 consecutive channels of one atom -> no cross-lane epilogue.
// EPI 0: D -> dst.  EPI 1: ssp(D + bias) -> dst.  EPI 2: hreg += D + bias; -> dst
template<int EPI>
static __device__ __forceinline__ void gemm_phase(const uint4* __restrict__ Wp, int g,
                                                  const unsigned* A_u, uint2* D2,
                                                  float hreg[2][2][4], const float* __restrict__ bias,
                                                  int w, int l){
    f32x4 acc00 = {0,0,0,0}, acc01 = {0,0,0,0}, acc10 = {0,0,0,0}, acc11 = {0,0,0,0};
    #pragma unroll
    for (int ks = 0; ks < 4; ks++){
        fp16x8 wa0 = ldW(Wp, g, ks, w * 2 + 0, l);
        fp16x8 wa1 = ldW(Wp, g, ks, w * 2 + 1, l);
        fp16x8 xb0 = ldX(A_u, 0, ks, l);
        fp16x8 xb1 = ldX(A_u, 16, ks, l);
        acc00 = __builtin_amdgcn_mfma_f32_16x16x32_f16(wa0, xb0, acc00, 0, 0, 0);
        acc01 = __builtin_amdgcn_mfma_f32_16x16x32_f16(wa0, xb1, acc01, 0, 0, 0);
        acc10 = __builtin_amdgcn_mfma_f32_16x16x32_f16(wa1, xb0, acc10, 0, 0, 0);
        acc11 = __builtin_amdgcn_mfma_f32_16x16x32_f16(wa1, xb1, acc11, 0, 0, 0);
    }
    #pragma unroll
    for (int chf = 0; chf < 2; chf++){
        int ch0 = (w * 2 + chf) * 16 + ((l >> 4) << 2);
        float4 bv = {0,0,0,0};
        if (EPI >= 1) bv = ld4(bias + ch0);
        #pragma unroll
        for (int af = 0; af < 2; af++){
            f32x4 a = (chf == 0) ? (af == 0 ? acc00 : acc01) : (af == 0 ? acc10 : acc11);
            int atom = af * 16 + (l & 15);
            float v0 = a[0] + bv.x, v1 = a[1] + bv.y, v2 = a[2] + bv.z, v3 = a[3] + bv.w;
            if (EPI == 1){ v0 = sspf(v0); v1 = sspf(v1); v2 = sspf(v2); v3 = sspf(v3); }
            if (EPI == 2){
                v0 += hreg[chf][af][0]; hreg[chf][af][0] = v0;
                v1 += hreg[chf][af][1]; hreg[chf][af][1] = v1;
                v2 += hreg[chf][af][2]; hreg[chf][af][2] = v2;
                v3 += hreg[chf][af][3]; hreg[chf][af][3] = v3;
            }
            D2[(atom << 5) + (((ch0 >> 2) ^ ((atom & 7) << 1)))] = make_uint2(packh(v0, v1), packh(v2, v3));
        }
    }
}

// ---- mega kernel: one block = one molecule, all 3 layers + per-molecule decoder ----
__global__ __launch_bounds__(256, 4) void k_mega(const int* __restrict__ z, const float* __restrict__ coord,
                                                 const float* __restrict__ emask, const float* __restrict__ amask,
                                                 const float* __restrict__ emb,
                                                 const uint4* __restrict__ Wp,
                                                 const float* __restrict__ o_b1, const float* __restrict__ o_b2,
                                                 const unsigned* __restrict__ Tb,
                                                 const float* __restrict__ dW1, const float* __restrict__ db1,
                                                 const float* __restrict__ dW2, const float* __restrict__ db2,
                                                 float* __restrict__ tempv, int nn){
    __shared__ __align__(16) unsigned hbf[32 * 64];     // f16 h (X input)
    __shared__ __align__(16) unsigned xfb[32 * 64];     // xf / t (f16)
    __shared__ __align__(16) unsigned mbu[32 * 64];     // edge messages m (f16)
    __shared__ int      pkE[32 * 32];                   // col | (t<<8)
    __shared__ int      cntL[32];
    __shared__ int      cntQ[8];
    __shared__ int      zL[32];
    __shared__ unsigned maskL[32];
    __shared__ float    cxyz[96];
    __shared__ float    amL[32];
    __shared__ float    hsb[NHF];

    int mol = blockIdx.x;
    int tid = threadIdx.x;
    int w = tid >> 6, l = tid & 63;
    int molA = mol * nn;
    int km = nn - 1;
    int ne = nn * km;

    uint2* hbf2 = reinterpret_cast<uint2*>(hbf);
    uint2* xfb2 = reinterpret_cast<uint2*>(xfb);

    // ---- cooperative staging ----
    if (tid < 32){ maskL[tid] = 0u; cntL[tid] = 0; }
    if (tid < 3 * nn) cxyz[tid] = coord[(size_t)molA * 3 + tid];
    if (tid < 32)     amL[tid] = (tid < nn) ? amask[molA + tid] : 0.0f;
    if (tid < 32)     zL[tid]  = (tid < nn) ? z[molA + tid] : 0;
    __syncthreads();
    for (int e = tid; e < ne; e += 256){
        if (emask[(size_t)molA * km + e] != 0.0f){
            int a = e / km, k = e - a * km;
            atomicOr(&maskL[a], 1u << k);
        }
    }

    // ---- h init: registers [chf][af][r] (ch-major C-layout) + f16 LDS copy ----
    float hreg[2][2][4];
    #pragma unroll
    for (int chf = 0; chf < 2; chf++){
        int ch0 = (w * 2 + chf) * 16 + ((l >> 4) << 2);
        #pragma unroll
        for (int af = 0; af < 2; af++){
            int atom = af * 16 + (l & 15);
            float4 v = {0,0,0,0};
            if (atom < nn) v = ld4(emb + (size_t)zL[atom] * NHF + ch0);
            hreg[chf][af][0] = v.x; hreg[chf][af][1] = v.y;
            hreg[chf][af][2] = v.z; hreg[chf][af][3] = v.w;
            hbf2[(atom << 5) + (((ch0 >> 2) ^ ((atom & 7) << 1)))] = make_uint2(packh(v.x, v.y), packh(v.z, v.w));
        }
    }
    __syncthreads();

    // ---- per-atom active-edge lists ----
    if (tid < nn){
        int ai = tid;
        unsigned msk = maskL[ai];
        float ax = cxyz[ai*3], ay = cxyz[ai*3+1], az = cxyz[ai*3+2];
        int cnt = 0;
        for (int k = 0; k < km; k++){
            int nb = k + (k >= ai ? 1 : 0);
            float dx = ax - cxyz[nb*3], dy = ay - cxyz[nb*3+1], dz = az - cxyz[nb*3+2];
            float r = sqrtf(dx*dx + dy*dy + dz*dz);
            int t = (int)(r * TINV + 0.5f);
            if (((msk >> k) & 1u) && t < TBL){
                pkE[ai * 32 + cnt] = nb | (t << 8);
                cnt++;
            }
        }
        cntL[ai] = cnt;
    }
    __syncthreads();
    // pad each atom's list to quad-max (multiple of 2); dummy -> T row TBL (zeros)
    if (tid < 32){
        int b4 = tid & ~3;
        int m0 = cntL[b4], m1 = cntL[b4+1], m2 = cntL[b4+2], m3 = cntL[b4+3];
        int mx = max(max(m0, m1), max(m2, m3));
        mx = (mx + 1) & ~1;
        for (int k = cntL[tid]; k < mx; k++) pkE[tid * 32 + k] = (TBL << 8);
        if (!(tid & 3)) cntQ[tid >> 2] = mx;
    }
    __syncthreads();

    int j16 = l & 15, g16 = l >> 4;
    for (int L = 0; L < LAYERS; L++){
        // in2f: xf = h @ W (no bias)
        gemm_phase<0>(Wp, L * 3 + 0, hbf, xfb2, hreg, o_b1, w, l);
        __syncthreads();
        // edge messages: 4 atoms/wave, 8 ch/lane, uint4 loads, f32 accumulation (v_fma_mix)
        const char* Tlj = (const char*)(Tb + (size_t)L * TROWS * 64) + (j16 << 4);
        for (int q = w; q < 8; q += 4){
            int a = (q << 2) + g16;
            int cnt = cntQ[q];
            const int* pe = &pkE[a * 32];
            float accf[8] = {0,0,0,0,0,0,0,0};
            for (int k = 0; k < cnt; k += 2){
                #pragma unroll
                for (int jj = 0; jj < 2; jj++){
                    int p = pe[k + jj];
                    uint4 tw = *reinterpret_cast<const uint4*>(Tlj + (p & ~0xFF));
                    int ca = p & 31;
                    uint4 xw = *reinterpret_cast<const uint4*>(&xfb[(ca << 6) + ((j16 ^ (ca & 7)) << 2)]);
                    f16x2 t0 = __builtin_bit_cast(f16x2, tw.x), t1 = __builtin_bit_cast(f16x2, tw.y);
                    f16x2 t2 = __builtin_bit_cast(f16x2, tw.z), t3 = __builtin_bit_cast(f16x2, tw.w);
                    f16x2 x0 = __builtin_bit_cast(f16x2, xw.x), x1 = __builtin_bit_cast(f16x2, xw.y);
                    f16x2 x2 = __builtin_bit_cast(f16x2, xw.z), x3 = __builtin_bit_cast(f16x2, xw.w);
                    accf[0] += (float)t0[0] * (float)x0[0];
                    accf[1] += (float)t0[1] * (float)x0[1];
                    accf[2] += (float)t1[0] * (float)x1[0];
                    accf[3] += (float)t1[1] * (float)x1[1];
                    accf[4] += (float)t2[0] * (float)x2[0];
                    accf[5] += (float)t2[1] * (float)x2[1];
                    accf[6] += (float)t3[0] * (float)x3[0];
                    accf[7] += (float)t3[1] * (float)x3[1];
                }
            }
            *reinterpret_cast<uint4*>(&mbu[(a << 6) + ((j16 ^ (a & 7)) << 2)]) =
                make_uint4(packh(accf[0], accf[1]), packh(accf[2], accf[3]),
                           packh(accf[4], accf[5]), packh(accf[6], accf[7]));
        }
        __syncthreads();
        // o1: t = ssp(m @ W + b1)
        gemm_phase<1>(Wp, L * 3 + 1, mbu, xfb2, hreg, o_b1 + L * NHF, w, l);
        __syncthreads();
        // o2: h(reg) += t @ W + b2 ; refresh h f16 copy
        gemm_phase<2>(Wp, L * 3 + 2, xfb, hbf2, hreg, o_b2 + L * NHF, w, l);
        __syncthreads();
    }

    // ---- readout: sum over atoms (cross-lane over l&15) + decoder -> tempv[mol] ----
    {
        float s[2][4];
        #pragma unroll
        for (int chf = 0; chf < 2; chf++)
            #pragma unroll
            for (int r = 0; r < 4; r++)
                s[chf][r] = hreg[chf][0][r] * amL[l & 15] + hreg[chf][1][r] * amL[16 + (l & 15)];
        #pragma unroll
        for (int o = 1; o < 16; o <<= 1){
            #pragma unroll
            for (int chf = 0; chf < 2; chf++)
                #pragma unroll
                for (int r = 0; r < 4; r++)
                    s[chf][r] += __shfl_xor(s[chf][r], o);
        }
        if (!(l & 15)){
            #pragma unroll
            for (int chf = 0; chf < 2; chf++)
                #pragma unroll
                for (int r = 0; r < 4; r++)
                    hsb[(w * 2 + chf) * 16 + ((l >> 4) << 2) + r] = s[chf][r];
        }
    }
    __syncthreads();
    // decoder: 256 threads = 64 outputs x 4 c-partitions, reduce in LDS (reuse pkE)
    {
        float* red = (float*)pkE;
        int o = tid & 63, part = tid >> 6;
        float u = 0.0f;
        #pragma unroll 8
        for (int c = part * 32; c < part * 32 + 32; c++)
            u = fmaf(hsb[c], dW1[c * 64 + o], u);
        red[part * 64 + o] = u;
    }
    __syncthreads();
    if (tid < 64){
        float u = ((float*)pkE)[tid] + ((float*)pkE)[64 + tid] + ((float*)pkE)[128 + tid]
                + ((float*)pkE)[192 + tid] + db1[tid];
        float p = sspf(u) * dW2[tid];
        #pragma unroll
        for (int o = 32; o > 0; o >>= 1) p += __shfl_down(p, o);
        if (tid == 0) tempv[mol] = p + db2[0];
    }
}

// ---- deterministic reaction scatter: pred[r] = sum_mol [ridx==r] temp*rsign (fixed order) ----
// Unrolled so LDS reads pipeline; the accumulate chain stays in strict ascending-i order
// (bit-identical to the serial loop), so output is deterministic AND unchanged.
__global__ __launch_bounds__(256) void k_pred(const float* __restrict__ tempv, const int* __restrict__ ridx,
                                              const float* __restrict__ rsign, float* __restrict__ pred,
                                              int nmol, int nreact){
    extern __shared__ float sh[];                 // [nmol] temp*rsign, then [nmol] ridx
    float* tv = sh;
    int*   ri = (int*)(sh + nmol);
    int tid = threadIdx.x;
    for (int i = tid; i < nmol; i += 256){
        tv[i] = tempv[i] * rsign[i];
        ri[i] = ridx[i];
    }
    __syncthreads();
    int r = blockIdx.x * 256 + tid;
    if (r >= nreact) return;
    float s = 0.0f;
    int i = 0;
    for (; i + 8 <= nmol; i += 8){
        #pragma unroll
        for (int j = 0; j < 8; j++){
            float v = tv[i + j];
            s += (ri[i + j] == r) ? v : 0.0f;
        }
    }
    for (; i < nmol; i++)
        s += (ri[i] == r) ? tv[i] : 0.0f;
    pred[r] = s;
}

extern "C" void kernel_launch(void* const* d_in, const int* in_sizes, int n_in,
                              void* d_out, int out_size, void* d_ws, size_t ws_size,
                              hipStream_t stream){
    const int*   z      = (const int*)  d_in[0];
    const float* coord  = (const float*)d_in[1];
    const float* amask  = (const float*)d_in[3];
    const float* emask  = (const float*)d_in[4];
    const int*   ridx   = (const int*)  d_in[5];
    const float* rsign  = (const float*)d_in[6];
    const float* emb    = (const float*)d_in[7];
    const float* in2f_W = (const float*)d_in[10];
    const float* f_W1   = (const float*)d_in[11];
    const float* f_b1   = (const float*)d_in[12];
    const float* f_W2   = (const float*)d_in[13];
    const float* f_b2   = (const float*)d_in[14];
    const float* o_W1   = (const float*)d_in[15];
    const float* o_b1   = (const float*)d_in[16];
    const float* o_W2   = (const float*)d_in[17];
    const float* o_b2   = (const float*)d_in[18];
    const float* dW1    = (const float*)d_in[19];
    const float* db1    = (const float*)d_in[20];
    const float* dW2    = (const float*)d_in[21];
    const float* db2    = (const float*)d_in[22];

    const int N  = in_sizes[0];
    const int B  = in_sizes[5];
    const int nn = N / B;
    (void)n_in; (void)ws_size;

    // workspace carve
    uint4*    Wp    = (uint4*)d_ws;                                      // 294912 B
    unsigned* Tb    = (unsigned*)((char*)d_ws + 9 * 2048 * 16);          // LAYERS*TROWS*256 B
    float*    tempv = (float*)((char*)Tb + (size_t)LAYERS * TROWS * 256);// B floats

    k_pack <<<72, 256, 0, stream>>>(in2f_W, o_W1, o_W2, Wp);
    k_table<<<dim3((TROWS + 7) / 8, LAYERS), 256, 0, stream>>>(f_W1, f_b1, f_W2, f_b2,
                                                               (unsigned short*)Tb);
    k_mega <<<B, 256, 0, stream>>>(z, coord, emask, amask, emb, Wp, o_b1, o_b2, Tb,
                                   dW1, db1, dW2, db2, tempv, nn);
    k_pred <<<(out_size + 255) / 256, 256, B * 8, stream>>>(tempv, ridx, rsign,
                                                            (float*)d_out, B, out_size);
}